// Round 3
// baseline (895.632 us; speedup 1.0000x reference)
//
#include <hip/hip_runtime.h>
#include <math.h>

#define NNODES 100000
#define NEDGES 1600000
#define DD 64
#define EPS 1e-8f

__device__ __forceinline__ float wave_sum(float v) {
    #pragma unroll
    for (int off = 32; off; off >>= 1) v += __shfl_xor(v, off, 64);
    return v;
}

__device__ __forceinline__ float hinner(float u, float v, float sgn) {
    return wave_sum(sgn * u * v);
}

__device__ __forceinline__ float cross_ratio(float r0, float r1, float r2, float r3, float sgn) {
    float A = hinner(r0, r2, sgn);
    float B = hinner(r1, r3, sgn);
    float C = hinner(r0, r3, sgn);
    float Dv = hinner(r1, r2, sgn);
    return (A * B) / (C * Dv + EPS);
}

__device__ __forceinline__ float restore_scale(float cr_i, float cr_c) {
    float ratio = cr_i / (cr_c + EPS);
    bool cond = (!__builtin_isnan(cr_c)) && (!__builtin_isnan(cr_i)) &&
                (fabsf(cr_c) > EPS) && (fabsf(cr_i) > EPS) && (ratio > EPS);
    float s = 1.0f;
    if (cond) {
        s = sqrtf(fabsf(ratio));
        if (!__builtin_isfinite(s)) s = 1.0f;
    }
    return s;
}

__device__ __forceinline__ unsigned short f2bf(float f) {
    unsigned u = __float_as_uint(f);
    unsigned r = (u + 0x7fffu + ((u >> 16) & 1u)) >> 16;
    return (unsigned short)r;
}

__device__ __forceinline__ float bf2f(unsigned short b) {
    return __uint_as_float(((unsigned)b) << 16);
}

__device__ __forceinline__ float bcast(float v, int lane) {
    return __int_as_float(__builtin_amdgcn_readlane(__float_as_int(v), lane));
}

// layer0: h0 = normalize(x @ W0 + b0), one wave per row; W0 column in VGPRs,
// broadcast x[k] via v_readlane. Store bf16.
__global__ __launch_bounds__(256) void k_layer0(const float* __restrict__ x,
                                                const float* __restrict__ W0,
                                                const float* __restrict__ b0,
                                                unsigned short* __restrict__ h0b) {
    int lane = threadIdx.x & 63;
    float w0[DD];
    #pragma unroll
    for (int k = 0; k < DD; k++) w0[k] = W0[k * DD + lane];
    float bv = b0[lane];
    int wid = (blockIdx.x * 256 + threadIdx.x) >> 6;
    int nw = (gridDim.x * 256) >> 6;
    for (int row = wid; row < NNODES; row += nw) {
        float xv = x[(size_t)row * DD + lane];
        float acc = bv;
        #pragma unroll
        for (int k = 0; k < DD; k++)
            acc = fmaf(bcast(xv, k), w0[k], acc);
        float n = sqrtf(wave_sum(acc * acc));
        h0b[(size_t)row * DD + lane] = f2bf(acc / (n + EPS));
    }
}

// degree histogram (int atomics)
__global__ __launch_bounds__(256) void k_hist(const int* __restrict__ ei,
                                              int* __restrict__ deg) {
    int tid = blockIdx.x * 256 + threadIdx.x;
    int stride = gridDim.x * 256;
    for (int e = tid; e < NEDGES; e += stride)
        atomicAdd(&deg[ei[NEDGES + e]], 1);
}

// single-block exclusive scan of degrees -> row_ptr[N+1] and cursor copy
__global__ __launch_bounds__(1024) void k_scan(const int* __restrict__ deg,
                                               int* __restrict__ row_ptr,
                                               int* __restrict__ cursor) {
    __shared__ int part[1024];
    int t = threadIdx.x;
    int lo = t * 98;
    int hi = lo + 98; if (hi > NNODES) hi = NNODES;
    if (lo > NNODES) lo = NNODES;
    int s = 0;
    for (int i = lo; i < hi; i++) s += deg[i];
    part[t] = s;
    __syncthreads();
    for (int off = 1; off < 1024; off <<= 1) {
        int v = (t >= off) ? part[t - off] : 0;
        __syncthreads();
        part[t] += v;
        __syncthreads();
    }
    int base = (t == 0) ? 0 : part[t - 1];
    for (int i = lo; i < hi; i++) {
        row_ptr[i] = base;
        cursor[i] = base;
        base += deg[i];
    }
    if (t == 1023) row_ptr[NNODES] = part[1023];
}

// fill CSR column (src) list via cursor atomics
__global__ __launch_bounds__(256) void k_fill(const int* __restrict__ ei,
                                              int* __restrict__ cursor,
                                              int* __restrict__ col) {
    int tid = blockIdx.x * 256 + threadIdx.x;
    int stride = gridDim.x * 256;
    for (int e = tid; e < NEDGES; e += stride) {
        int d = ei[NEDGES + e];
        int pos = atomicAdd(&cursor[d], 1);
        col[pos] = ei[e];
    }
}

// head kernel (1 wave): recompute rows 0..3 (and their neighbors' h0 rows)
// in pure fp32 from x/W0, so s1/s2 match the fp32 reference; bf16 never
// touches the cross-ratio path.
__global__ void k_head(const float* __restrict__ x,
                       const float* __restrict__ W0, const float* __restrict__ b0,
                       const int* __restrict__ row_ptr, const int* __restrict__ col,
                       const float* __restrict__ Wm, const float* __restrict__ bm,
                       const float* __restrict__ W1, const float* __restrict__ b1,
                       float* __restrict__ scal) {
    int lane = threadIdx.x;
    float sgn = (lane == 63) ? -1.0f : 1.0f;

    float w0[DD];
    #pragma unroll
    for (int k = 0; k < DD; k++) w0[k] = W0[k * DD + lane];
    float b0v = b0[lane];

    float cr_init = cross_ratio(x[lane], x[DD + lane], x[2 * DD + lane], x[3 * DD + lane], sgn);

    // fp32 h0 row recompute
    auto h0row = [&](int r) -> float {
        float xv = x[(size_t)r * DD + lane];
        float acc = b0v;
        #pragma unroll
        for (int k = 0; k < DD; k++)
            acc = fmaf(__shfl(xv, k, 64), w0[k], acc);
        float n = sqrtf(wave_sum(acc * acc));
        return acc / (n + EPS);
    };

    float cr0 = cross_ratio(h0row(0), h0row(1), h0row(2), h0row(3), sgn);

    float h2r[4];
    #pragma unroll 1
    for (int r = 0; r < 4; r++) {
        int start = row_ptr[r], end = row_ptr[r + 1];
        float sum = 0.0f;
        for (int i = start; i < end; i++)
            sum += h0row(col[i]);
        float ct = fmaxf((float)(end - start), 1.0f);
        float av = sum / ct;
        float acc = bm[lane];
        for (int k = 0; k < DD; k++)
            acc = fmaf(__shfl(av, k, 64), Wm[k * DD + lane], acc);
        float n = sqrtf(wave_sum(acc * acc));
        h2r[r] = acc / (n + EPS);
    }
    float cr_cur = cross_ratio(h2r[0], h2r[1], h2r[2], h2r[3], sgn);
    float s1 = restore_scale(cr0, cr_cur);

    float fr[4];
    #pragma unroll 1
    for (int r = 0; r < 4; r++) {
        float hv = h2r[r] * s1;
        float acc = b1[lane];
        for (int k = 0; k < DD; k++)
            acc = fmaf(__shfl(hv, k, 64), W1[k * DD + lane], acc);
        float n = sqrtf(wave_sum(acc * acc));
        fr[r] = fmaxf(acc / (n + EPS), 0.0f);
    }
    float cr2 = cross_ratio(fr[0], fr[1], fr[2], fr[3], sgn);
    float s2 = restore_scale(cr_init, cr2);

    if (lane == 0) { scal[0] = s1; scal[1] = s2; }
}

// fused: gather-mean over CSR -> Wm GEMV -> norm -> *s1 -> W1 GEMV -> norm -> relu -> *s2
// One wave per dst row; 4 edges in flight (16 lanes x 4 bf16-channels each).
// All shfls/loads execute with the FULL wave active (ds_bpermute returns 0
// from inactive source lanes — predicate by multiply, never by branch).
__global__ __launch_bounds__(256) void k_gather(const unsigned short* __restrict__ h0b,
                                                const int* __restrict__ row_ptr,
                                                const int* __restrict__ col,
                                                const float* __restrict__ Wm,
                                                const float* __restrict__ bm,
                                                const float* __restrict__ W1,
                                                const float* __restrict__ b1,
                                                const float* __restrict__ scal,
                                                float* __restrict__ out) {
    int lane = threadIdx.x & 63;
    int q = lane & 15;   // channel quad: channels 4q..4q+3
    int g = lane >> 4;   // edge group 0..3
    float wm[DD], w1[DD];
    #pragma unroll
    for (int k = 0; k < DD; k++) { wm[k] = Wm[k * DD + lane]; w1[k] = W1[k * DD + lane]; }
    float bmv = bm[lane], b1v = b1[lane];
    float s1 = scal[0], s2 = scal[1];
    int wid = (blockIdx.x * 256 + threadIdx.x) >> 6;
    int nw = (gridDim.x * 256) >> 6;
    for (int row = wid; row < NNODES; row += nw) {
        int start = row_ptr[row], end = row_ptr[row + 1];
        float ax = 0.0f, ay = 0.0f, az = 0.0f, aw = 0.0f;
        for (int cb = start; cb < end; cb += 64) {
            int c = (cb + lane < end) ? col[cb + lane] : 0;
            int m = end - cb; if (m > 64) m = 64;
            #pragma unroll 4
            for (int j = 0; j < m; j += 4) {
                int e = j + g;
                bool val = e < m;
                int esafe = val ? e : 0;
                int src = __shfl(c, esafe, 64);      // full wave active
                const ushort4* p = (const ushort4*)(h0b + (size_t)src * DD + q * 4);
                ushort4 u = *p;                       // clamped -> valid address
                float f = val ? 1.0f : 0.0f;
                ax = fmaf(f, bf2f(u.x), ax);
                ay = fmaf(f, bf2f(u.y), ay);
                az = fmaf(f, bf2f(u.z), az);
                aw = fmaf(f, bf2f(u.w), aw);
            }
        }
        // reduce over the 4 edge groups
        ax += __shfl_xor(ax, 16, 64); ax += __shfl_xor(ax, 32, 64);
        ay += __shfl_xor(ay, 16, 64); ay += __shfl_xor(ay, 32, 64);
        az += __shfl_xor(az, 16, 64); az += __shfl_xor(az, 32, 64);
        aw += __shfl_xor(aw, 16, 64); aw += __shfl_xor(aw, 32, 64);
        float inv = 1.0f / fmaxf((float)(end - start), 1.0f);
        float ac[4] = {ax * inv, ay * inv, az * inv, aw * inv};
        // GEMV Wm: channel k lives at lane k>>2, component k&3
        float acc = bmv;
        #pragma unroll
        for (int k = 0; k < DD; k++)
            acc = fmaf(bcast(ac[k & 3], k >> 2), wm[k], acc);
        float n = sqrtf(wave_sum(acc * acc));
        float h2 = (acc / (n + EPS)) * s1;
        // GEMV W1: h2 is lane=channel
        float acc2 = b1v;
        #pragma unroll
        for (int k = 0; k < DD; k++)
            acc2 = fmaf(bcast(h2, k), w1[k], acc2);
        n = sqrtf(wave_sum(acc2 * acc2));
        out[(size_t)row * DD + lane] = fmaxf(acc2 / (n + EPS), 0.0f) * s2;
    }
}

extern "C" void kernel_launch(void* const* d_in, const int* in_sizes, int n_in,
                              void* d_out, int out_size, void* d_ws, size_t ws_size,
                              hipStream_t stream) {
    const float* x  = (const float*)d_in[0];
    const int*   ei = (const int*)d_in[1];
    const float* W0 = (const float*)d_in[2];
    const float* b0 = (const float*)d_in[3];
    const float* Wm = (const float*)d_in[4];
    const float* bm = (const float*)d_in[5];
    const float* W1 = (const float*)d_in[6];
    const float* b1 = (const float*)d_in[7];
    float* out = (float*)d_out;

    // ws layout (~20.4 MB)
    unsigned short* h0b = (unsigned short*)d_ws;            // N*64 bf16 = 12.8 MB
    int* deg     = (int*)(h0b + (size_t)NNODES * DD);       // N
    int* row_ptr = deg + NNODES;                            // N+1
    int* cursor  = row_ptr + NNODES + 1;                    // N
    int* col     = cursor + NNODES;                         // E = 6.4 MB
    float* scal  = (float*)(col + NEDGES);                  // 2

    hipMemsetAsync(deg, 0, NNODES * sizeof(int), stream);

    k_layer0<<<1024, 256, 0, stream>>>(x, W0, b0, h0b);
    k_hist  <<<1024, 256, 0, stream>>>(ei, deg);
    k_scan  <<<1, 1024, 0, stream>>>(deg, row_ptr, cursor);
    k_fill  <<<1024, 256, 0, stream>>>(ei, cursor, col);
    k_head  <<<1, 64, 0, stream>>>(x, W0, b0, row_ptr, col, Wm, bm, W1, b1, scal);
    k_gather<<<2048, 256, 0, stream>>>(h0b, row_ptr, col, Wm, bm, W1, b1, scal, out);
}

// Round 4
// 499.316 us; speedup vs baseline: 1.7937x; 1.7937x over previous
//
#include <hip/hip_runtime.h>
#include <math.h>

#define NNODES 100000
#define NEDGES 1600000
#define DD 64
#define EPS 1e-8f
#define SCAN_B 1024
#define SCAN_NB ((NNODES + SCAN_B - 1) / SCAN_B)   // 98

__device__ __forceinline__ float wave_sum(float v) {
    #pragma unroll
    for (int off = 32; off; off >>= 1) v += __shfl_xor(v, off, 64);
    return v;
}

__device__ __forceinline__ float hinner(float u, float v, float sgn) {
    return wave_sum(sgn * u * v);
}

__device__ __forceinline__ float cross_ratio(float r0, float r1, float r2, float r3, float sgn) {
    float A = hinner(r0, r2, sgn);
    float B = hinner(r1, r3, sgn);
    float C = hinner(r0, r3, sgn);
    float Dv = hinner(r1, r2, sgn);
    return (A * B) / (C * Dv + EPS);
}

__device__ __forceinline__ float restore_scale(float cr_i, float cr_c) {
    float ratio = cr_i / (cr_c + EPS);
    bool cond = (!__builtin_isnan(cr_c)) && (!__builtin_isnan(cr_i)) &&
                (fabsf(cr_c) > EPS) && (fabsf(cr_i) > EPS) && (ratio > EPS);
    float s = 1.0f;
    if (cond) {
        s = sqrtf(fabsf(ratio));
        if (!__builtin_isfinite(s)) s = 1.0f;
    }
    return s;
}

__device__ __forceinline__ unsigned short f2bf(float f) {
    unsigned u = __float_as_uint(f);
    unsigned r = (u + 0x7fffu + ((u >> 16) & 1u)) >> 16;
    return (unsigned short)r;
}

__device__ __forceinline__ float bf2f(unsigned short b) {
    return __uint_as_float(((unsigned)b) << 16);
}

__device__ __forceinline__ float bcast(float v, int lane) {
    return __int_as_float(__builtin_amdgcn_readlane(__float_as_int(v), lane));
}

// layer0: h0 = normalize(x @ W0 + b0), one wave per row; W0 column in VGPRs.
__global__ __launch_bounds__(256) void k_layer0(const float* __restrict__ x,
                                                const float* __restrict__ W0,
                                                const float* __restrict__ b0,
                                                unsigned short* __restrict__ h0b) {
    int lane = threadIdx.x & 63;
    float w0[DD];
    #pragma unroll
    for (int k = 0; k < DD; k++) w0[k] = W0[k * DD + lane];
    float bv = b0[lane];
    int wid = (blockIdx.x * 256 + threadIdx.x) >> 6;
    int nw = (gridDim.x * 256) >> 6;
    for (int row = wid; row < NNODES; row += nw) {
        float xv = x[(size_t)row * DD + lane];
        float acc = bv;
        #pragma unroll
        for (int k = 0; k < DD; k++)
            acc = fmaf(bcast(xv, k), w0[k], acc);
        float n = sqrtf(wave_sum(acc * acc));
        h0b[(size_t)row * DD + lane] = f2bf(acc / (n + EPS));
    }
}

// degree histogram (int atomics)
__global__ __launch_bounds__(256) void k_hist(const int* __restrict__ ei,
                                              int* __restrict__ deg) {
    int tid = blockIdx.x * 256 + threadIdx.x;
    int stride = gridDim.x * 256;
    for (int e = tid; e < NEDGES; e += stride)
        atomicAdd(&deg[ei[NEDGES + e]], 1);
}

// scan phase 1: per-block exclusive scan of deg into row_ptr, block totals out
__global__ __launch_bounds__(SCAN_B) void k_scan1(const int* __restrict__ deg,
                                                  int* __restrict__ row_ptr,
                                                  int* __restrict__ blksum) {
    __shared__ int part[SCAN_B];
    int t = threadIdx.x;
    int i = blockIdx.x * SCAN_B + t;
    int v = (i < NNODES) ? deg[i] : 0;
    part[t] = v;
    __syncthreads();
    for (int off = 1; off < SCAN_B; off <<= 1) {
        int u = (t >= off) ? part[t - off] : 0;
        __syncthreads();
        part[t] += u;
        __syncthreads();
    }
    if (i < NNODES) row_ptr[i] = part[t] - v;  // block-local exclusive
    if (t == SCAN_B - 1) blksum[blockIdx.x] = part[t];
}

// scan phase 2: 1 block scans the 98 block sums -> exclusive block offsets
__global__ __launch_bounds__(128) void k_scan2(const int* __restrict__ blksum,
                                               int* __restrict__ blkoff) {
    __shared__ int s[128];
    int t = threadIdx.x;
    int v = (t < SCAN_NB) ? blksum[t] : 0;
    s[t] = v;
    __syncthreads();
    for (int off = 1; off < 128; off <<= 1) {
        int u = (t >= off) ? s[t - off] : 0;
        __syncthreads();
        s[t] += u;
        __syncthreads();
    }
    if (t < SCAN_NB) blkoff[t] = s[t] - v;
}

// scan phase 3: add block offsets; produce final row_ptr and cursor copy
__global__ __launch_bounds__(SCAN_B) void k_scan3(int* __restrict__ row_ptr,
                                                  const int* __restrict__ blkoff,
                                                  int* __restrict__ cursor) {
    int t = threadIdx.x;
    int i = blockIdx.x * SCAN_B + t;
    if (i < NNODES) {
        int v = row_ptr[i] + blkoff[blockIdx.x];
        row_ptr[i] = v;
        cursor[i] = v;
    }
    if (i == 0) row_ptr[NNODES] = NEDGES;
}

// fill CSR column (src) list via cursor atomics
__global__ __launch_bounds__(256) void k_fill(const int* __restrict__ ei,
                                              int* __restrict__ cursor,
                                              int* __restrict__ col) {
    int tid = blockIdx.x * 256 + threadIdx.x;
    int stride = gridDim.x * 256;
    for (int e = tid; e < NEDGES; e += stride) {
        int d = ei[NEDGES + e];
        int pos = atomicAdd(&cursor[d], 1);
        col[pos] = ei[e];
    }
}

// head kernel (4 waves): rows 0..3 through the full pipeline in fp32 -> s1, s2.
// Wave w owns cross-ratio row w; cross-ratios computed redundantly per wave.
__global__ __launch_bounds__(256) void k_head(const float* __restrict__ x,
                       const float* __restrict__ W0, const float* __restrict__ b0,
                       const int* __restrict__ row_ptr, const int* __restrict__ col,
                       const float* __restrict__ Wm, const float* __restrict__ bm,
                       const float* __restrict__ W1, const float* __restrict__ b1,
                       float* __restrict__ scal) {
    __shared__ float hs[4][DD];
    __shared__ float h2s[4][DD];
    __shared__ float frs[4][DD];
    int lane = threadIdx.x & 63;
    int w = threadIdx.x >> 6;
    float sgn = (lane == 63) ? -1.0f : 1.0f;

    float w0[DD];
    #pragma unroll
    for (int k = 0; k < DD; k++) w0[k] = W0[k * DD + lane];
    float b0v = b0[lane];

    auto h0row = [&](int r) -> float {
        float xv = x[(size_t)r * DD + lane];
        float acc = b0v;
        #pragma unroll
        for (int k = 0; k < DD; k++)
            acc = fmaf(bcast(xv, k), w0[k], acc);
        float n = sqrtf(wave_sum(acc * acc));
        return acc / (n + EPS);
    };

    hs[w][lane] = h0row(w);

    // aggregate row w's neighbors (fp32 recompute) + Wm GEMV + normalize
    int start = row_ptr[w], end = row_ptr[w + 1];
    float sum = 0.0f;
    for (int i = start; i < end; i++) sum += h0row(col[i]);
    float av = sum / fmaxf((float)(end - start), 1.0f);
    float acc = bm[lane];
    #pragma unroll
    for (int k = 0; k < DD; k++)
        acc = fmaf(bcast(av, k), Wm[k * DD + lane], acc);
    float n = sqrtf(wave_sum(acc * acc));
    h2s[w][lane] = acc / (n + EPS);
    __syncthreads();

    float cr_init = cross_ratio(x[lane], x[DD + lane], x[2 * DD + lane], x[3 * DD + lane], sgn);
    float cr0 = cross_ratio(hs[0][lane], hs[1][lane], hs[2][lane], hs[3][lane], sgn);
    float cr_cur = cross_ratio(h2s[0][lane], h2s[1][lane], h2s[2][lane], h2s[3][lane], sgn);
    float s1 = restore_scale(cr0, cr_cur);

    float hv = h2s[w][lane] * s1;
    float acc2 = b1[lane];
    #pragma unroll
    for (int k = 0; k < DD; k++)
        acc2 = fmaf(bcast(hv, k), W1[k * DD + lane], acc2);
    n = sqrtf(wave_sum(acc2 * acc2));
    frs[w][lane] = fmaxf(acc2 / (n + EPS), 0.0f);
    __syncthreads();

    if (w == 0) {
        float cr2 = cross_ratio(frs[0][lane], frs[1][lane], frs[2][lane], frs[3][lane], sgn);
        float s2 = restore_scale(cr_init, cr2);
        if (lane == 0) { scal[0] = s1; scal[1] = s2; }
    }
}

// fused: gather-mean over CSR -> Wm GEMV -> norm -> *s1 -> W1 GEMV -> norm -> relu -> *s2
// One wave per dst row; 4 edges in flight (16 lanes x 4 bf16-channels each).
// All shfls/loads execute with the FULL wave active (ds_bpermute returns 0
// from inactive source lanes — predicate by multiply, never by branch).
__global__ __launch_bounds__(256) void k_gather(const unsigned short* __restrict__ h0b,
                                                const int* __restrict__ row_ptr,
                                                const int* __restrict__ col,
                                                const float* __restrict__ Wm,
                                                const float* __restrict__ bm,
                                                const float* __restrict__ W1,
                                                const float* __restrict__ b1,
                                                const float* __restrict__ scal,
                                                float* __restrict__ out) {
    int lane = threadIdx.x & 63;
    int q = lane & 15;   // channel quad: channels 4q..4q+3
    int g = lane >> 4;   // edge group 0..3
    float wm[DD], w1[DD];
    #pragma unroll
    for (int k = 0; k < DD; k++) { wm[k] = Wm[k * DD + lane]; w1[k] = W1[k * DD + lane]; }
    float bmv = bm[lane], b1v = b1[lane];
    float s1 = scal[0], s2 = scal[1];
    int wid = (blockIdx.x * 256 + threadIdx.x) >> 6;
    int nw = (gridDim.x * 256) >> 6;
    for (int row = wid; row < NNODES; row += nw) {
        int start = row_ptr[row], end = row_ptr[row + 1];
        float ax = 0.0f, ay = 0.0f, az = 0.0f, aw = 0.0f;
        for (int cb = start; cb < end; cb += 64) {
            int c = (cb + lane < end) ? col[cb + lane] : 0;
            int m = end - cb; if (m > 64) m = 64;
            #pragma unroll 4
            for (int j = 0; j < m; j += 4) {
                int e = j + g;
                bool val = e < m;
                int esafe = val ? e : 0;
                int src = __shfl(c, esafe, 64);      // full wave active
                const ushort4* p = (const ushort4*)(h0b + (size_t)src * DD + q * 4);
                ushort4 u = *p;                       // clamped -> valid address
                float f = val ? 1.0f : 0.0f;
                ax = fmaf(f, bf2f(u.x), ax);
                ay = fmaf(f, bf2f(u.y), ay);
                az = fmaf(f, bf2f(u.z), az);
                aw = fmaf(f, bf2f(u.w), aw);
            }
        }
        ax += __shfl_xor(ax, 16, 64); ax += __shfl_xor(ax, 32, 64);
        ay += __shfl_xor(ay, 16, 64); ay += __shfl_xor(ay, 32, 64);
        az += __shfl_xor(az, 16, 64); az += __shfl_xor(az, 32, 64);
        aw += __shfl_xor(aw, 16, 64); aw += __shfl_xor(aw, 32, 64);
        float inv = 1.0f / fmaxf((float)(end - start), 1.0f);
        float ac[4] = {ax * inv, ay * inv, az * inv, aw * inv};
        float acc = bmv;
        #pragma unroll
        for (int k = 0; k < DD; k++)
            acc = fmaf(bcast(ac[k & 3], k >> 2), wm[k], acc);
        float n = sqrtf(wave_sum(acc * acc));
        float h2 = (acc / (n + EPS)) * s1;
        float acc2 = b1v;
        #pragma unroll
        for (int k = 0; k < DD; k++)
            acc2 = fmaf(bcast(h2, k), w1[k], acc2);
        n = sqrtf(wave_sum(acc2 * acc2));
        out[(size_t)row * DD + lane] = fmaxf(acc2 / (n + EPS), 0.0f) * s2;
    }
}

extern "C" void kernel_launch(void* const* d_in, const int* in_sizes, int n_in,
                              void* d_out, int out_size, void* d_ws, size_t ws_size,
                              hipStream_t stream) {
    const float* x  = (const float*)d_in[0];
    const int*   ei = (const int*)d_in[1];
    const float* W0 = (const float*)d_in[2];
    const float* b0 = (const float*)d_in[3];
    const float* Wm = (const float*)d_in[4];
    const float* bm = (const float*)d_in[5];
    const float* W1 = (const float*)d_in[6];
    const float* b1 = (const float*)d_in[7];
    float* out = (float*)d_out;

    // ws layout (~20.4 MB)
    unsigned short* h0b = (unsigned short*)d_ws;            // N*64 bf16 = 12.8 MB
    int* deg     = (int*)(h0b + (size_t)NNODES * DD);       // N
    int* row_ptr = deg + NNODES;                            // N+1
    int* cursor  = row_ptr + NNODES + 1;                    // N
    int* col     = cursor + NNODES;                         // E = 6.4 MB
    int* blksum  = col + NEDGES;                            // 128
    int* blkoff  = blksum + 128;                            // 128
    float* scal  = (float*)(blkoff + 128);                  // 2

    hipMemsetAsync(deg, 0, NNODES * sizeof(int), stream);

    k_layer0<<<1024, 256, 0, stream>>>(x, W0, b0, h0b);
    k_hist  <<<1024, 256, 0, stream>>>(ei, deg);
    k_scan1 <<<SCAN_NB, SCAN_B, 0, stream>>>(deg, row_ptr, blksum);
    k_scan2 <<<1, 128, 0, stream>>>(blksum, blkoff);
    k_scan3 <<<SCAN_NB, SCAN_B, 0, stream>>>(row_ptr, blkoff, cursor);
    k_fill  <<<1024, 256, 0, stream>>>(ei, cursor, col);
    k_head  <<<1, 256, 0, stream>>>(x, W0, b0, row_ptr, col, Wm, bm, W1, b1, scal);
    k_gather<<<2048, 256, 0, stream>>>(h0b, row_ptr, col, Wm, bm, W1, b1, scal, out);
}

// Round 5
// 442.400 us; speedup vs baseline: 2.0245x; 1.1287x over previous
//
#include <hip/hip_runtime.h>
#include <math.h>

#define NNODES 100000
#define NEDGES 1600000
#define DD 64
#define EPS 1e-8f
#define SCAN_B 1024
#define SCAN_NB ((NNODES + SCAN_B - 1) / SCAN_B)   // 98

typedef unsigned short us8 __attribute__((ext_vector_type(8)));

__device__ __forceinline__ float wave_sum(float v) {
    #pragma unroll
    for (int off = 32; off; off >>= 1) v += __shfl_xor(v, off, 64);
    return v;
}

__device__ __forceinline__ float hinner(float u, float v, float sgn) {
    return wave_sum(sgn * u * v);
}

__device__ __forceinline__ float cross_ratio(float r0, float r1, float r2, float r3, float sgn) {
    float A = hinner(r0, r2, sgn);
    float B = hinner(r1, r3, sgn);
    float C = hinner(r0, r3, sgn);
    float Dv = hinner(r1, r2, sgn);
    return (A * B) / (C * Dv + EPS);
}

__device__ __forceinline__ float restore_scale(float cr_i, float cr_c) {
    float ratio = cr_i / (cr_c + EPS);
    bool cond = (!__builtin_isnan(cr_c)) && (!__builtin_isnan(cr_i)) &&
                (fabsf(cr_c) > EPS) && (fabsf(cr_i) > EPS) && (ratio > EPS);
    float s = 1.0f;
    if (cond) {
        s = sqrtf(fabsf(ratio));
        if (!__builtin_isfinite(s)) s = 1.0f;
    }
    return s;
}

__device__ __forceinline__ unsigned short f2bf(float f) {
    unsigned u = __float_as_uint(f);
    unsigned r = (u + 0x7fffu + ((u >> 16) & 1u)) >> 16;
    return (unsigned short)r;
}

__device__ __forceinline__ float bf2f(unsigned short b) {
    return __uint_as_float(((unsigned)b) << 16);
}

__device__ __forceinline__ float bcast(float v, int lane) {
    return __int_as_float(__builtin_amdgcn_readlane(__float_as_int(v), lane));
}

// layer0: h0 = normalize(x @ W0 + b0). One wave per row. x row is broadcast
// via wave-uniform scalar loads (SMEM pipe); W0 column lives in VGPRs; the
// FMA chain is split 4 ways for ILP.
__global__ __launch_bounds__(256, 5) void k_layer0(const float* __restrict__ x,
                                                   const float* __restrict__ W0,
                                                   const float* __restrict__ b0,
                                                   unsigned short* __restrict__ h0b) {
    int lane = threadIdx.x & 63;
    float w0[DD];
    #pragma unroll
    for (int k = 0; k < DD; k++) w0[k] = W0[k * DD + lane];
    float bv = b0[lane];
    int wid = (blockIdx.x * 256 + threadIdx.x) >> 6;
    int nw = (gridDim.x * 256) >> 6;
    for (int row = wid; row < NNODES; row += nw) {
        int row_u = __builtin_amdgcn_readfirstlane(row);
        const float* xr = x + (size_t)row_u * DD;
        float a0 = bv, a1 = 0.0f, a2 = 0.0f, a3 = 0.0f;
        #pragma unroll
        for (int k = 0; k < DD; k += 4) {
            a0 = fmaf(xr[k],     w0[k],     a0);
            a1 = fmaf(xr[k + 1], w0[k + 1], a1);
            a2 = fmaf(xr[k + 2], w0[k + 2], a2);
            a3 = fmaf(xr[k + 3], w0[k + 3], a3);
        }
        float acc = (a0 + a1) + (a2 + a3);
        float n = sqrtf(wave_sum(acc * acc));
        h0b[(size_t)row_u * DD + lane] = f2bf(acc / (n + EPS));
    }
}

// degree histogram (int atomics)
__global__ __launch_bounds__(256) void k_hist(const int* __restrict__ ei,
                                              int* __restrict__ deg) {
    int tid = blockIdx.x * 256 + threadIdx.x;
    int stride = gridDim.x * 256;
    for (int e = tid; e < NEDGES; e += stride)
        atomicAdd(&deg[ei[NEDGES + e]], 1);
}

// scan phase 1: per-block exclusive scan of deg into row_ptr, block totals out
__global__ __launch_bounds__(SCAN_B) void k_scan1(const int* __restrict__ deg,
                                                  int* __restrict__ row_ptr,
                                                  int* __restrict__ blksum) {
    __shared__ int part[SCAN_B];
    int t = threadIdx.x;
    int i = blockIdx.x * SCAN_B + t;
    int v = (i < NNODES) ? deg[i] : 0;
    part[t] = v;
    __syncthreads();
    for (int off = 1; off < SCAN_B; off <<= 1) {
        int u = (t >= off) ? part[t - off] : 0;
        __syncthreads();
        part[t] += u;
        __syncthreads();
    }
    if (i < NNODES) row_ptr[i] = part[t] - v;
    if (t == SCAN_B - 1) blksum[blockIdx.x] = part[t];
}

// scan phase 2: 1 block scans the 98 block sums -> exclusive block offsets
__global__ __launch_bounds__(128) void k_scan2(const int* __restrict__ blksum,
                                               int* __restrict__ blkoff) {
    __shared__ int s[128];
    int t = threadIdx.x;
    int v = (t < SCAN_NB) ? blksum[t] : 0;
    s[t] = v;
    __syncthreads();
    for (int off = 1; off < 128; off <<= 1) {
        int u = (t >= off) ? s[t - off] : 0;
        __syncthreads();
        s[t] += u;
        __syncthreads();
    }
    if (t < SCAN_NB) blkoff[t] = s[t] - v;
}

// scan phase 3: add block offsets; produce final row_ptr and cursor copy
__global__ __launch_bounds__(SCAN_B) void k_scan3(int* __restrict__ row_ptr,
                                                  const int* __restrict__ blkoff,
                                                  int* __restrict__ cursor) {
    int t = threadIdx.x;
    int i = blockIdx.x * SCAN_B + t;
    if (i < NNODES) {
        int v = row_ptr[i] + blkoff[blockIdx.x];
        row_ptr[i] = v;
        cursor[i] = v;
    }
    if (i == 0) row_ptr[NNODES] = NEDGES;
}

// fill CSR column (src) list via cursor atomics
__global__ __launch_bounds__(256) void k_fill(const int* __restrict__ ei,
                                              int* __restrict__ cursor,
                                              int* __restrict__ col) {
    int tid = blockIdx.x * 256 + threadIdx.x;
    int stride = gridDim.x * 256;
    for (int e = tid; e < NEDGES; e += stride) {
        int d = ei[NEDGES + e];
        int pos = atomicAdd(&cursor[d], 1);
        col[pos] = ei[e];
    }
}

// pure gather-mean: agg[dst] = mean of h0b[src] over CSR neighbors.
// 8 lanes per edge (16 B ushort8 each), 8 edges in flight per wave-iter.
// Tiny VGPR footprint -> max occupancy for latency hiding.
__global__ __launch_bounds__(256) void k_agg(const unsigned short* __restrict__ h0b,
                                             const int* __restrict__ row_ptr,
                                             const int* __restrict__ col,
                                             float* __restrict__ agg) {
    int lane = threadIdx.x & 63;
    int q = lane & 7;    // channel octet: channels 8q..8q+7
    int g = lane >> 3;   // edge group 0..7
    int wid = (blockIdx.x * 256 + threadIdx.x) >> 6;
    int nw = (gridDim.x * 256) >> 6;
    for (int row = wid; row < NNODES; row += nw) {
        int start = row_ptr[row], end = row_ptr[row + 1];
        float s[8] = {0, 0, 0, 0, 0, 0, 0, 0};
        for (int cb = start; cb < end; cb += 64) {
            int c = (cb + lane < end) ? col[cb + lane] : 0;
            int m = end - cb; if (m > 64) m = 64;
            for (int j = 0; j < m; j += 8) {
                int e = j + g;
                bool val = e < m;
                int esafe = val ? e : 0;
                int src = __shfl(c, esafe, 64);      // full wave active
                us8 u = *(const us8*)(h0b + (size_t)src * DD + q * 8);
                float f = val ? 1.0f : 0.0f;
                #pragma unroll
                for (int i = 0; i < 8; i++)
                    s[i] = fmaf(f, bf2f(u[i]), s[i]);
            }
        }
        #pragma unroll
        for (int i = 0; i < 8; i++) {
            s[i] += __shfl_xor(s[i], 8, 64);
            s[i] += __shfl_xor(s[i], 16, 64);
            s[i] += __shfl_xor(s[i], 32, 64);
        }
        if (g == 0) {
            float inv = 1.0f / fmaxf((float)(end - start), 1.0f);
            float4* dst = (float4*)(agg + (size_t)row * DD + q * 8);
            float4 o0 = {s[0] * inv, s[1] * inv, s[2] * inv, s[3] * inv};
            float4 o1 = {s[4] * inv, s[5] * inv, s[6] * inv, s[7] * inv};
            dst[0] = o0;
            dst[1] = o1;
        }
    }
}

// head kernel (4 waves): rows 0..3 through the full pipeline in fp32 -> s1, s2.
__global__ __launch_bounds__(256) void k_head(const float* __restrict__ x,
                       const float* __restrict__ W0, const float* __restrict__ b0,
                       const int* __restrict__ row_ptr, const int* __restrict__ col,
                       const float* __restrict__ Wm, const float* __restrict__ bm,
                       const float* __restrict__ W1, const float* __restrict__ b1,
                       float* __restrict__ scal) {
    __shared__ float hs[4][DD];
    __shared__ float h2s[4][DD];
    __shared__ float frs[4][DD];
    int lane = threadIdx.x & 63;
    int w = threadIdx.x >> 6;
    float sgn = (lane == 63) ? -1.0f : 1.0f;

    float w0[DD];
    #pragma unroll
    for (int k = 0; k < DD; k++) w0[k] = W0[k * DD + lane];
    float b0v = b0[lane];

    auto h0row = [&](int r) -> float {
        float xv = x[(size_t)r * DD + lane];
        float acc = b0v;
        #pragma unroll
        for (int k = 0; k < DD; k++)
            acc = fmaf(bcast(xv, k), w0[k], acc);
        float n = sqrtf(wave_sum(acc * acc));
        return acc / (n + EPS);
    };

    hs[w][lane] = h0row(w);

    int start = row_ptr[w], end = row_ptr[w + 1];
    float sum = 0.0f;
    for (int i = start; i < end; i++) sum += h0row(col[i]);
    float av = sum / fmaxf((float)(end - start), 1.0f);
    float acc = bm[lane];
    #pragma unroll
    for (int k = 0; k < DD; k++)
        acc = fmaf(bcast(av, k), Wm[k * DD + lane], acc);
    float n = sqrtf(wave_sum(acc * acc));
    h2s[w][lane] = acc / (n + EPS);
    __syncthreads();

    float cr_init = cross_ratio(x[lane], x[DD + lane], x[2 * DD + lane], x[3 * DD + lane], sgn);
    float cr0 = cross_ratio(hs[0][lane], hs[1][lane], hs[2][lane], hs[3][lane], sgn);
    float cr_cur = cross_ratio(h2s[0][lane], h2s[1][lane], h2s[2][lane], h2s[3][lane], sgn);
    float s1 = restore_scale(cr0, cr_cur);

    float hv = h2s[w][lane] * s1;
    float acc2 = b1[lane];
    #pragma unroll
    for (int k = 0; k < DD; k++)
        acc2 = fmaf(bcast(hv, k), W1[k * DD + lane], acc2);
    n = sqrtf(wave_sum(acc2 * acc2));
    frs[w][lane] = fmaxf(acc2 / (n + EPS), 0.0f);
    __syncthreads();

    if (w == 0) {
        float cr2 = cross_ratio(frs[0][lane], frs[1][lane], frs[2][lane], frs[3][lane], sgn);
        float s2 = restore_scale(cr_init, cr2);
        if (lane == 0) { scal[0] = s1; scal[1] = s2; }
    }
}

// dense per-row: data(=agg, in place) -> Wm GEMV -> norm -> *s1 -> W1 GEMV
// -> norm -> relu -> *s2. Weights VGPR-resident (launch_bounds cap 170),
// FMA chains split 4-way. One pointer for in/out (same buffer, row-local).
__global__ __launch_bounds__(256, 3) void k_mlp(float* data,
                                                const float* __restrict__ Wm,
                                                const float* __restrict__ bm,
                                                const float* __restrict__ W1,
                                                const float* __restrict__ b1,
                                                const float* __restrict__ scal) {
    int lane = threadIdx.x & 63;
    float wm[DD], w1[DD];
    #pragma unroll
    for (int k = 0; k < DD; k++) { wm[k] = Wm[k * DD + lane]; w1[k] = W1[k * DD + lane]; }
    float bmv = bm[lane], b1v = b1[lane];
    float s1 = scal[0], s2 = scal[1];
    int wid = (blockIdx.x * 256 + threadIdx.x) >> 6;
    int nw = (gridDim.x * 256) >> 6;
    for (int row = wid; row < NNODES; row += nw) {
        float av = data[(size_t)row * DD + lane];
        float a0 = bmv, a1 = 0.0f, a2 = 0.0f, a3 = 0.0f;
        #pragma unroll
        for (int k = 0; k < DD; k += 4) {
            a0 = fmaf(bcast(av, k),     wm[k],     a0);
            a1 = fmaf(bcast(av, k + 1), wm[k + 1], a1);
            a2 = fmaf(bcast(av, k + 2), wm[k + 2], a2);
            a3 = fmaf(bcast(av, k + 3), wm[k + 3], a3);
        }
        float acc = (a0 + a1) + (a2 + a3);
        float n = sqrtf(wave_sum(acc * acc));
        float h2 = (acc / (n + EPS)) * s1;
        float c0 = b1v, c1 = 0.0f, c2 = 0.0f, c3 = 0.0f;
        #pragma unroll
        for (int k = 0; k < DD; k += 4) {
            c0 = fmaf(bcast(h2, k),     w1[k],     c0);
            c1 = fmaf(bcast(h2, k + 1), w1[k + 1], c1);
            c2 = fmaf(bcast(h2, k + 2), w1[k + 2], c2);
            c3 = fmaf(bcast(h2, k + 3), w1[k + 3], c3);
        }
        float acc2 = (c0 + c1) + (c2 + c3);
        n = sqrtf(wave_sum(acc2 * acc2));
        data[(size_t)row * DD + lane] = fmaxf(acc2 / (n + EPS), 0.0f) * s2;
    }
}

extern "C" void kernel_launch(void* const* d_in, const int* in_sizes, int n_in,
                              void* d_out, int out_size, void* d_ws, size_t ws_size,
                              hipStream_t stream) {
    const float* x  = (const float*)d_in[0];
    const int*   ei = (const int*)d_in[1];
    const float* W0 = (const float*)d_in[2];
    const float* b0 = (const float*)d_in[3];
    const float* Wm = (const float*)d_in[4];
    const float* bm = (const float*)d_in[5];
    const float* W1 = (const float*)d_in[6];
    const float* b1 = (const float*)d_in[7];
    float* out = (float*)d_out;

    // ws layout (~20.5 MB)
    unsigned short* h0b = (unsigned short*)d_ws;            // N*64 bf16 = 12.8 MB
    int* deg     = (int*)(h0b + (size_t)NNODES * DD);       // N
    int* row_ptr = deg + NNODES;                            // N+1
    int* cursor  = row_ptr + NNODES + 1;                    // N
    int* col     = cursor + NNODES;                         // E = 6.4 MB
    int* blksum  = col + NEDGES;                            // 128
    int* blkoff  = blksum + 128;                            // 128
    float* scal  = (float*)(blkoff + 128);                  // 2

    hipMemsetAsync(deg, 0, NNODES * sizeof(int), stream);

    k_layer0<<<2048, 256, 0, stream>>>(x, W0, b0, h0b);
    k_hist  <<<1024, 256, 0, stream>>>(ei, deg);
    k_scan1 <<<SCAN_NB, SCAN_B, 0, stream>>>(deg, row_ptr, blksum);
    k_scan2 <<<1, 128, 0, stream>>>(blksum, blkoff);
    k_scan3 <<<SCAN_NB, SCAN_B, 0, stream>>>(row_ptr, blkoff, cursor);
    k_fill  <<<1024, 256, 0, stream>>>(ei, cursor, col);
    k_agg   <<<4096, 256, 0, stream>>>(h0b, row_ptr, col, out);   // agg staged in d_out
    k_head  <<<1, 256, 0, stream>>>(x, W0, b0, row_ptr, col, Wm, bm, W1, b1, scal);
    k_mlp   <<<2048, 256, 0, stream>>>(out, Wm, bm, W1, b1, scal);
}